// Round 5
// baseline (6497.623 us; speedup 1.0000x reference)
//
#include <hip/hip_runtime.h>
#include <hip/hip_fp16.h>
#include <math.h>

// Problem constants (fixed shapes from the reference)
#define BB 32
#define SS 256
#define EE 300
#define EP 304          // E padded to multiple of 16
#define HH 256
#define TT 19           // NUM_TAGS + START + STOP
#define START_TAG 17
#define STOP_TAG 18
#define BS 8192         // B*S
#define GIN_PER_DIR (8192*1024)

__device__ __forceinline__ float sigm(float x){ return 1.0f/(1.0f+expf(-x)); }

__device__ __forceinline__ float2 up16(unsigned int u){
  __half2 h = __builtin_bit_cast(__half2, u);
  return __half22float2(h);          // .x = low half (even k), .y = high (odd k)
}

// 8 MACs: uint4 = 8 fp16 weights over k-span 8; ha covers k..k+3, hb k+4..k+7
__device__ __forceinline__ float mac8(uint4 W, float4 ha, float4 hb, float acc){
  float2 a = up16(W.x); acc += a.x*ha.x + a.y*ha.y;
  float2 b = up16(W.y); acc += b.x*ha.z + b.y*ha.w;
  float2 c = up16(W.z); acc += c.x*hb.x + c.y*hb.y;
  float2 d = up16(W.w); acc += d.x*hb.z + d.y*hb.w;
  return acc;
}

// ---------------- ws layout (float offsets) ----------------
// x_pad : [BS][304]            off 0          size 2490368
// WT    : [304][2048]          off 2490368    size 622592   (transposed+padded, cols permuted to (j*4+g))
// bias2 : [2048]               off 3112960    size 2048
// W16   : fp16 Whh, packed     off 3115008    size 65536 floats (=262144 uints view; 1 MB)
//         uint4 index: ((d*2+part)*16 + c)*1024 + tid ; c = jj*4+g ; part 0=resident,1=streamed
//         dword q, half l -> k = kpart*64 + part*32 + jj*8 + q*2 + l   (tid = kpart*256+urow)
// gin   : [2][BS][1024]        off 3639296    size 16777216 (preacts, interleaved row j*4+g)
// hseq  : [BS][512]            off 20416512   size 4194304
// emit  : [BS][19]             off 24610816   size 155648
// ptr   : [BS][19] (int)       off 24766464   size 155648
// nll   : [32]                 off 24922112

// -------- embed gather + mask, pad E to 304 with zeros --------
__global__ void k_embed(const int* __restrict__ wi, const int* __restrict__ msk,
                        const float* __restrict__ emb, float* __restrict__ x){
  int id = blockIdx.x*256 + threadIdx.x;        // BS*76 float4 slots
  if (id >= BS*76) return;
  int row = id / 76, q = id - row*76;
  float4 v = make_float4(0.f,0.f,0.f,0.f);
  if (q < 75){                                   // 75*4 = 300 real elements
    const float4* e4 = (const float4*)emb;       // emb rows are 1200B = 16B aligned
    v = e4[(size_t)wi[row]*75 + q];
    float m = (float)msk[row];
    v.x*=m; v.y*=m; v.z*=m; v.w*=m;
  }
  ((float4*)x)[(size_t)row*76 + q] = v;
}

// -------- transpose Wih into WT[304][2048] with PERMUTED columns, build bias --------
// column n: dd = n>>10 (dir), r = n&1023, j = r>>2 (h-row), g = r&3 (gate)
__global__ void k_prep_wt(const float* __restrict__ Wih_f, const float* __restrict__ Wih_b,
                          const float* __restrict__ bih_f, const float* __restrict__ bhh_f,
                          const float* __restrict__ bih_b, const float* __restrict__ bhh_b,
                          float* __restrict__ WT, float* __restrict__ bias){
  int id = blockIdx.x*256 + threadIdx.x;
  if (id < 304*2048){
    int k = id >> 11, n = id & 2047;
    int dd = n >> 10, r = n & 1023, j = r >> 2, g = r & 3;
    int orow = g*256 + j;
    float v = 0.f;
    if (k < 300) v = dd ? Wih_b[orow*300 + k] : Wih_f[orow*300 + k];
    WT[id] = v;
  } else {
    int n = id - 304*2048;
    if (n < 2048){
      int dd = n >> 10, r = n & 1023, j = r >> 2, g = r & 3;
      int orow = g*256 + j;
      bias[n] = dd ? (bih_b[orow] + bhh_b[orow]) : (bih_f[orow] + bhh_f[orow]);
    }
  }
}

// -------- pack Whh to fp16, layout for k_lstm v5 (see ws map) --------
__global__ void k_prep_whh16(const float* __restrict__ Whh_f, const float* __restrict__ Whh_b,
                             unsigned int* __restrict__ out){
  int id = blockIdx.x*256 + threadIdx.x;        // 262144 uints
  int q = id & 3;
  int t = (id >> 2) & 1023;
  int c = (id >> 12) & 15;
  int p = (id >> 16) & 1;
  int d = id >> 17;
  int kpart = t >> 8, urow = t & 255;
  int jj = c >> 2, g = c & 3;
  int k = kpart*64 + p*32 + jj*8 + q*2;
  const float* W = d ? Whh_b : Whh_f;
  float w0 = W[(size_t)(g*256 + urow)*256 + k];
  float w1 = W[(size_t)(g*256 + urow)*256 + k + 1];
  unsigned u0 = __half_as_ushort(__float2half(w0));
  unsigned u1 = __half_as_ushort(__float2half(w1));
  out[id] = (u1 << 16) | u0;
}

// -------- input-gate GEMM: gin[dd][row][r] = x @ WT[:,n] + bias[n] --------
__global__ __launch_bounds__(256) void k_gemm(const float* __restrict__ x,
      const float* __restrict__ WT, const float* __restrict__ bias,
      float* __restrict__ gin){
  __shared__ float As[16][65];
  __shared__ float Bs[16][64];
  int tid = threadIdx.x;
  int tx = tid & 15, ty = tid >> 4;
  int n0 = blockIdx.x * 64, m0 = blockIdx.y * 64;
  float acc[4][4] = {};
  for (int kt = 0; kt < 19; ++kt){
    int k0 = kt*16;
    #pragma unroll
    for (int i = 0; i < 4; ++i){
      int idx = tid + i*256;
      int ak = idx & 15, am = idx >> 4;
      As[ak][am] = x[(size_t)(m0+am)*304 + (k0+ak)];
      int bn = idx & 63, bk = idx >> 6;
      Bs[bk][bn] = WT[(size_t)(k0+bk)*2048 + (n0+bn)];
    }
    __syncthreads();
    #pragma unroll
    for (int k = 0; k < 16; ++k){
      float a0 = As[k][ty*4+0], a1 = As[k][ty*4+1], a2 = As[k][ty*4+2], a3 = As[k][ty*4+3];
      float b0 = Bs[k][tx*4+0], b1 = Bs[k][tx*4+1], b2 = Bs[k][tx*4+2], b3 = Bs[k][tx*4+3];
      acc[0][0]+=a0*b0; acc[0][1]+=a0*b1; acc[0][2]+=a0*b2; acc[0][3]+=a0*b3;
      acc[1][0]+=a1*b0; acc[1][1]+=a1*b1; acc[1][2]+=a1*b2; acc[1][3]+=a1*b3;
      acc[2][0]+=a2*b0; acc[2][1]+=a2*b1; acc[2][2]+=a2*b2; acc[2][3]+=a2*b3;
      acc[3][0]+=a3*b0; acc[3][1]+=a3*b1; acc[3][2]+=a3*b2; acc[3][3]+=a3*b3;
    }
    __syncthreads();
  }
  #pragma unroll
  for (int i = 0; i < 4; ++i){
    int m = m0 + ty*4 + i;
    #pragma unroll
    for (int j = 0; j < 4; ++j){
      int n = n0 + tx*4 + j;
      int dd = n >> 10, r = n & 1023;
      gin[(size_t)dd*GIN_PER_DIR + (size_t)m*1024 + r] = acc[i][j] + bias[n];
    }
  }
}

// -------- BiLSTM recurrence v5: single-CU per (b,d), fp16 weights --------
// half register-resident (loaded once), half streamed from L2 each step.
// thread (kpart=tid>>8, urow=tid&255): 4 gate partials of h-row urow over
// k in [kpart*64, kpart*64+64). fp32 h, fp32 accumulate (precision-safe).
// __launch_bounds__(1024,4): grants 128 VGPR/wave (round-3 spill fix).
__global__ __launch_bounds__(1024, 4) void k_lstm(const float* __restrict__ gin,
                 const uint4* __restrict__ W16, float* __restrict__ hseq){
  int tid = threadIdx.x;
  int b = blockIdx.x & 31, d = blockIdx.x >> 5;
  int kpart = tid >> 8;
  const uint4* wres = W16 + ((size_t)(d*2 + 0)*16)*1024 + tid;
  const uint4* wstr = W16 + ((size_t)(d*2 + 1)*16)*1024 + tid;
  const float* gb = gin + (size_t)d*GIN_PER_DIR + (size_t)b*SS*1024;

  __shared__ float hs[256];
  __shared__ float4 gl4[1024];
  if (tid < 256) hs[tid] = 0.f;
  float c = 0.f;

  // resident half: 16 uint4 = 64 VGPRs, loaded once
  uint4 w[16];
  #pragma unroll
  for (int i = 0; i < 16; ++i) w[i] = wres[i*1024];
  __syncthreads();

  const float4* hs4 = (const float4*)hs;
  for (int s = 0; s < SS; ++s){
    int t = d ? (SS-1-s) : s;
    float4 gv = make_float4(0.f,0.f,0.f,0.f);
    if (tid < 256) gv = ((const float4*)(gb + (size_t)t*1024))[tid];  // prefetch

    float acc0 = 0.f, acc1 = 0.f, acc2 = 0.f, acc3 = 0.f;

    // start stream pipeline: chunk jj=0 (c = 0*4+g)
    uint4 cur0 = wstr[0*1024], cur1 = wstr[1*1024], cur2 = wstr[2*1024], cur3 = wstr[3*1024];

    // resident part: k_local in [0,32), h indices kpart*16 + jj*2 (+1)
    #pragma unroll
    for (int jj = 0; jj < 4; ++jj){
      float4 ha = hs4[kpart*16 + jj*2];
      float4 hb = hs4[kpart*16 + jj*2 + 1];
      acc0 = mac8(w[jj*4+0], ha, hb, acc0);
      acc1 = mac8(w[jj*4+1], ha, hb, acc1);
      acc2 = mac8(w[jj*4+2], ha, hb, acc2);
      acc3 = mac8(w[jj*4+3], ha, hb, acc3);
    }
    // streamed part: k_local in [32,64), h indices kpart*16 + 8 + jj*2 (+1)
    #pragma unroll
    for (int jj = 0; jj < 4; ++jj){
      uint4 n0, n1, n2, n3;
      if (jj < 3){
        n0 = wstr[((jj+1)*4+0)*1024]; n1 = wstr[((jj+1)*4+1)*1024];
        n2 = wstr[((jj+1)*4+2)*1024]; n3 = wstr[((jj+1)*4+3)*1024];
      }
      float4 ha = hs4[kpart*16 + 8 + jj*2];
      float4 hb = hs4[kpart*16 + 8 + jj*2 + 1];
      acc0 = mac8(cur0, ha, hb, acc0);
      acc1 = mac8(cur1, ha, hb, acc1);
      acc2 = mac8(cur2, ha, hb, acc2);
      acc3 = mac8(cur3, ha, hb, acc3);
      if (jj < 3){ cur0 = n0; cur1 = n1; cur2 = n2; cur3 = n3; }
    }

    gl4[tid] = make_float4(acc0, acc1, acc2, acc3);
    __syncthreads();
    if (tid < 256){
      float4 p0 = gl4[tid], p1 = gl4[256+tid], p2 = gl4[512+tid], p3 = gl4[768+tid];
      float iv = sigm (p0.x + p1.x + p2.x + p3.x + gv.x);
      float fv = sigm (p0.y + p1.y + p2.y + p3.y + gv.y);
      float gg = tanhf(p0.z + p1.z + p2.z + p3.z + gv.z);
      float ov = sigm (p0.w + p1.w + p2.w + p3.w + gv.w);
      c = fv*c + iv*gg;
      float hv = ov*tanhf(c);
      hs[tid] = hv;
      hseq[((size_t)(b*SS + t))*512 + d*256 + tid] = hv;
    }
    __syncthreads();
  }
}

// -------- tag logits: emit[row][t] = hseq[row] . W_tag[t] + b_tag[t] --------
__global__ void k_emit(const float* __restrict__ hseq, const float* __restrict__ Wtag,
                       const float* __restrict__ btag, float* __restrict__ emit){
  int id = blockIdx.x*256 + threadIdx.x;
  if (id >= BS*TT) return;
  int row = id / TT, tg = id - row*TT;
  const float4* hp = (const float4*)(hseq + (size_t)row*512);
  const float4* wp = (const float4*)(Wtag + (size_t)tg*512);
  float acc = btag[tg];
  #pragma unroll 8
  for (int k = 0; k < 128; ++k){
    float4 h = hp[k], w = wp[k];
    acc += h.x*w.x + h.y*w.y + h.z*w.z + h.w*w.w;
  }
  emit[id] = acc;
}

// -------- CRF NLL (forward algorithm + gold score), one wave per batch --------
__global__ void k_crf(const float* __restrict__ emit, const int* __restrict__ msk,
                      const int* __restrict__ lab, const float* __restrict__ trans,
                      float* __restrict__ nll){
  int b = blockIdx.x, tid = threadIdx.x;
  __shared__ float tr[361];
  __shared__ float al[19];
  for (int i = tid; i < 361; i += 64) tr[i] = trans[i];
  const float* eb = emit + (size_t)b*SS*TT;
  const int* mb = msk + b*SS;
  const int* lb = lab + b*SS;
  __syncthreads();
  float gp = 0.f; int ln = 0;
  for (int t = tid; t < SS; t += 64){
    int m = mb[t];
    ln += m;
    if (m){
      int l = lb[t];
      int p = t ? lb[t-1] : START_TAG;
      gp += tr[p*19 + l] + eb[t*19 + l];
    }
  }
  for (int off = 32; off; off >>= 1){ gp += __shfl_down(gp, off); ln += __shfl_down(ln, off); }
  float gold = 0.f;
  if (tid == 0){
    int lt = lb[ln - 1];
    gold = gp + tr[lt*19 + STOP_TAG];
  }
  if (tid < 19) al[tid] = eb[tid] + tr[START_TAG*19 + tid];
  __syncthreads();
  for (int t = 1; t < SS; ++t){
    int m = mb[t];
    float nv = 0.f;
    if (tid < 19){
      float mx = -1e30f;
      for (int p = 0; p < 19; ++p){ float v = al[p] + tr[p*19 + tid]; mx = fmaxf(mx, v); }
      float sum = 0.f;
      for (int p = 0; p < 19; ++p) sum += expf(al[p] + tr[p*19 + tid] - mx);
      nv = mx + logf(sum) + eb[t*19 + tid];
    }
    __syncthreads();
    if (tid < 19 && m) al[tid] = nv;
    __syncthreads();
  }
  if (tid == 0){
    float mx = -1e30f;
    for (int c2 = 0; c2 < 19; ++c2) mx = fmaxf(mx, al[c2] + tr[c2*19 + STOP_TAG]);
    float sum = 0.f;
    for (int c2 = 0; c2 < 19; ++c2) sum += expf(al[c2] + tr[c2*19 + STOP_TAG] - mx);
    nll[b] = (mx + logf(sum)) - gold;
  }
}

// -------- Viterbi decode, one wave per batch; writes tags (as float) to d_out[1..] --------
__global__ void k_vit(const float* __restrict__ emit, const int* __restrict__ msk,
                      const float* __restrict__ trans, int* __restrict__ ptr,
                      float* __restrict__ out){
  int b = blockIdx.x, tid = threadIdx.x;
  __shared__ float tr[361];
  __shared__ float dl[19];
  __shared__ int tg[256];
  for (int i = tid; i < 361; i += 64) tr[i] = trans[i];
  const float* eb = emit + (size_t)b*SS*TT;
  const int* mb = msk + b*SS;
  int* pb = ptr + (size_t)b*SS*TT;
  if (tid < 19) dl[tid] = eb[tid] + tr[START_TAG*19 + tid];
  __syncthreads();
  for (int t = 1; t < SS; ++t){
    int m = mb[t];
    float best = -1e30f; int bp = 0;
    if (tid < 19){
      for (int p = 0; p < 19; ++p){
        float v = dl[p] + tr[p*19 + tid];
        if (v > best){ best = v; bp = p; }       // strict > == first-max (jnp.argmax)
      }
    }
    __syncthreads();
    if (tid < 19){
      if (m){ dl[tid] = best + eb[t*19 + tid]; pb[t*19 + tid] = bp; }
      else  { pb[t*19 + tid] = tid; }            // identity pass-through when padded
    }
    __syncthreads();
  }
  if (tid == 0){
    float bv = -1e30f; int bl = 0;
    for (int c2 = 0; c2 < 19; ++c2){
      float v = dl[c2] + tr[c2*19 + STOP_TAG];
      if (v > bv){ bv = v; bl = c2; }
    }
    tg[SS-1] = bl;
    for (int t = SS-1; t > 0; --t) tg[t-1] = pb[t*19 + tg[t]];
  }
  __syncthreads();
  for (int t = tid; t < SS; t += 64)
    out[1 + b*SS + t] = (float)(tg[t] * mb[t]);
}

// -------- final loss reduce: d_out[0] = sum(nll)/B --------
__global__ void k_final(const float* __restrict__ nll, float* __restrict__ out){
  int tid = threadIdx.x;
  float v = (tid < 32) ? nll[tid] : 0.f;
  for (int off = 32; off; off >>= 1) v += __shfl_down(v, off);
  if (tid == 0) out[0] = v * (1.0f/32.0f);
}

extern "C" void kernel_launch(void* const* d_in, const int* in_sizes, int n_in,
                              void* d_out, int out_size, void* d_ws, size_t ws_size,
                              hipStream_t stream){
  const int*   wi    = (const int*)d_in[0];
  const int*   msk   = (const int*)d_in[1];
  const int*   lab   = (const int*)d_in[2];
  // d_in[3] labels_token, d_in[4] data_type: unused (data_type==1 branch)
  const float* emb   = (const float*)d_in[5];
  const float* Wih_f = (const float*)d_in[6];
  const float* Whh_f = (const float*)d_in[7];
  const float* bih_f = (const float*)d_in[8];
  const float* bhh_f = (const float*)d_in[9];
  const float* Wih_b = (const float*)d_in[10];
  const float* Whh_b = (const float*)d_in[11];
  const float* bih_b = (const float*)d_in[12];
  const float* bhh_b = (const float*)d_in[13];
  const float* Wtag  = (const float*)d_in[14];
  const float* btag  = (const float*)d_in[15];
  const float* trans = (const float*)d_in[16];

  float* ws   = (float*)d_ws;
  float* x    = ws;
  float* WT   = ws + 2490368;
  float* bias = ws + 3112960;
  unsigned int* W16u = (unsigned int*)(ws + 3115008);
  uint4* W16  = (uint4*)W16u;
  float* gin  = ws + 3639296;
  float* hseq = ws + 20416512;
  float* emit = ws + 24610816;
  int*   ptr  = (int*)(ws + 24766464);
  float* nll  = ws + 24922112;
  float* out  = (float*)d_out;

  hipLaunchKernelGGL(k_embed,      dim3(2432),    dim3(256),  0, stream, wi, msk, emb, x);
  hipLaunchKernelGGL(k_prep_wt,    dim3(2440),    dim3(256),  0, stream,
                     Wih_f, Wih_b, bih_f, bhh_f, bih_b, bhh_b, WT, bias);
  hipLaunchKernelGGL(k_prep_whh16, dim3(1024),    dim3(256),  0, stream, Whh_f, Whh_b, W16u);
  hipLaunchKernelGGL(k_gemm,       dim3(32,128),  dim3(256),  0, stream, x, WT, bias, gin);
  hipLaunchKernelGGL(k_lstm,       dim3(64),      dim3(1024), 0, stream, gin, W16, hseq);
  hipLaunchKernelGGL(k_emit,       dim3(608),     dim3(256),  0, stream, hseq, Wtag, btag, emit);
  hipLaunchKernelGGL(k_crf,        dim3(32),      dim3(64),   0, stream, emit, msk, lab, trans, nll);
  hipLaunchKernelGGL(k_vit,        dim3(32),      dim3(64),   0, stream, emit, msk, trans, ptr, out);
  hipLaunchKernelGGL(k_final,      dim3(1),       dim3(64),   0, stream, nll, out);
}

// Round 6
// 2126.417 us; speedup vs baseline: 3.0557x; 3.0557x over previous
//
#include <hip/hip_runtime.h>
#include <hip/hip_fp16.h>
#include <math.h>

// Problem constants (fixed shapes from the reference)
#define BB 32
#define SS 256
#define EE 300
#define EP 304          // E padded to multiple of 16
#define HH 256
#define TT 19           // NUM_TAGS + START + STOP
#define START_TAG 17
#define STOP_TAG 18
#define BS 8192         // B*S
#define GIN_PER_DIR (8192*1024)

__device__ __forceinline__ float sigm(float x){ return 1.0f/(1.0f+expf(-x)); }

__device__ __forceinline__ float2 up16(unsigned int u){
  __half2 h = __builtin_bit_cast(__half2, u);
  return __half22float2(h);          // .x = low half (even k), .y = high half (odd k)
}

// 8 MACs: uint4 = 8 fp16 weights over k-span 8; ha covers k..k+3, hb k+4..k+7
__device__ __forceinline__ float mac8(uint4 W, float4 ha, float4 hb, float acc){
  float2 a = up16(W.x); acc += a.x*ha.x + a.y*ha.y;
  float2 b = up16(W.y); acc += b.x*ha.z + b.y*ha.w;
  float2 c = up16(W.z); acc += c.x*hb.x + c.y*hb.y;
  float2 d = up16(W.w); acc += d.x*hb.z + d.y*hb.w;
  return acc;
}

// ---------------- ws layout (float offsets) ----------------
// x_pad : [BS][304]            off 0          size 2490368
// WT    : [304][2048]          off 2490368    size 622592   (transposed+padded, cols permuted to (j*4+g))
// bias2 : [2048]               off 3112960    size 2048
// W16   : fp16 Whh packed      off 3115008    size 262144 floats used (1 MB)
//         uint4 index: (d*32 + q)*1024 + tid ; q = u*4+g (u=0..7 k-chunk, g=gate)
//         tid = kpart*256+urow ; dword j holds k = kpart*64 + u*8 + j*2 (+1 in high half)
// gin   : [2][BS][1024]        off 3639296    size 16777216 (preacts, interleaved row j*4+g)
// hseq  : [BS][512]            off 20416512   size 4194304
// emit  : [BS][19]             off 24610816   size 155648
// ptr   : [BS][19] (int)       off 24766464   size 155648
// nll   : [32]                 off 24922112

// -------- embed gather + mask, pad E to 304 with zeros --------
__global__ void k_embed(const int* __restrict__ wi, const int* __restrict__ msk,
                        const float* __restrict__ emb, float* __restrict__ x){
  int id = blockIdx.x*256 + threadIdx.x;        // BS*76 float4 slots
  if (id >= BS*76) return;
  int row = id / 76, q = id - row*76;
  float4 v = make_float4(0.f,0.f,0.f,0.f);
  if (q < 75){                                   // 75*4 = 300 real elements
    const float4* e4 = (const float4*)emb;       // emb rows are 1200B = 16B aligned
    v = e4[(size_t)wi[row]*75 + q];
    float m = (float)msk[row];
    v.x*=m; v.y*=m; v.z*=m; v.w*=m;
  }
  ((float4*)x)[(size_t)row*76 + q] = v;
}

// -------- transpose Wih into WT[304][2048] with PERMUTED columns, build bias --------
// column n: dd = n>>10 (dir), r = n&1023, j = r>>2 (h-row), g = r&3 (gate)
__global__ void k_prep_wt(const float* __restrict__ Wih_f, const float* __restrict__ Wih_b,
                          const float* __restrict__ bih_f, const float* __restrict__ bhh_f,
                          const float* __restrict__ bih_b, const float* __restrict__ bhh_b,
                          float* __restrict__ WT, float* __restrict__ bias){
  int id = blockIdx.x*256 + threadIdx.x;
  if (id < 304*2048){
    int k = id >> 11, n = id & 2047;
    int dd = n >> 10, r = n & 1023, j = r >> 2, g = r & 3;
    int orow = g*256 + j;
    float v = 0.f;
    if (k < 300) v = dd ? Wih_b[orow*300 + k] : Wih_f[orow*300 + k];
    WT[id] = v;
  } else {
    int n = id - 304*2048;
    if (n < 2048){
      int dd = n >> 10, r = n & 1023, j = r >> 2, g = r & 3;
      int orow = g*256 + j;
      bias[n] = dd ? (bih_b[orow] + bhh_b[orow]) : (bih_f[orow] + bhh_f[orow]);
    }
  }
}

// -------- pack Whh to fp16 for k_lstm v6 (layout in ws map) --------
__global__ void k_prep_whh16(const float* __restrict__ Whh_f, const float* __restrict__ Whh_b,
                             unsigned int* __restrict__ out){
  int id = blockIdx.x*256 + threadIdx.x;        // 262144 uints
  int j   = id & 3;
  int rst = id >> 2;
  int tid = rst & 1023;
  int q   = (rst >> 10) & 31;
  int d   = rst >> 15;
  int kpart = tid >> 8, urow = tid & 255;
  int u = q >> 2, g = q & 3;
  int k = kpart*64 + u*8 + j*2;
  const float* W = d ? Whh_b : Whh_f;
  float w0 = W[(size_t)(g*256 + urow)*256 + k];
  float w1 = W[(size_t)(g*256 + urow)*256 + k + 1];
  unsigned u0 = __half_as_ushort(__float2half(w0));
  unsigned u1 = __half_as_ushort(__float2half(w1));
  out[id] = (u1 << 16) | u0;
}

// -------- input-gate GEMM: gin[dd][row][r] = x @ WT[:,n] + bias[n] --------
__global__ __launch_bounds__(256) void k_gemm(const float* __restrict__ x,
      const float* __restrict__ WT, const float* __restrict__ bias,
      float* __restrict__ gin){
  __shared__ float As[16][65];
  __shared__ float Bs[16][64];
  int tid = threadIdx.x;
  int tx = tid & 15, ty = tid >> 4;
  int n0 = blockIdx.x * 64, m0 = blockIdx.y * 64;
  float acc[4][4] = {};
  for (int kt = 0; kt < 19; ++kt){
    int k0 = kt*16;
    #pragma unroll
    for (int i = 0; i < 4; ++i){
      int idx = tid + i*256;
      int ak = idx & 15, am = idx >> 4;
      As[ak][am] = x[(size_t)(m0+am)*304 + (k0+ak)];
      int bn = idx & 63, bk = idx >> 6;
      Bs[bk][bn] = WT[(size_t)(k0+bk)*2048 + (n0+bn)];
    }
    __syncthreads();
    #pragma unroll
    for (int k = 0; k < 16; ++k){
      float a0 = As[k][ty*4+0], a1 = As[k][ty*4+1], a2 = As[k][ty*4+2], a3 = As[k][ty*4+3];
      float b0 = Bs[k][tx*4+0], b1 = Bs[k][tx*4+1], b2 = Bs[k][tx*4+2], b3 = Bs[k][tx*4+3];
      acc[0][0]+=a0*b0; acc[0][1]+=a0*b1; acc[0][2]+=a0*b2; acc[0][3]+=a0*b3;
      acc[1][0]+=a1*b0; acc[1][1]+=a1*b1; acc[1][2]+=a1*b2; acc[1][3]+=a1*b3;
      acc[2][0]+=a2*b0; acc[2][1]+=a2*b1; acc[2][2]+=a2*b2; acc[2][3]+=a2*b3;
      acc[3][0]+=a3*b0; acc[3][1]+=a3*b1; acc[3][2]+=a3*b2; acc[3][3]+=a3*b3;
    }
    __syncthreads();
  }
  #pragma unroll
  for (int i = 0; i < 4; ++i){
    int m = m0 + ty*4 + i;
    #pragma unroll
    for (int j = 0; j < 4; ++j){
      int n = n0 + tx*4 + j;
      int dd = n >> 10, r = n & 1023;
      gin[(size_t)dd*GIN_PER_DIR + (size_t)m*1024 + r] = acc[i][j] + bias[n];
    }
  }
}

// -------- BiLSTM recurrence v6: single-CU per (b,d), fp16 streamed weights --------
// k-split-4 mapping (tid = kpart*256 + urow): thread computes 4 gate partials of
// h-row urow over k in [kpart*64, kpart*64+64). 32 uint4 weight loads/thread/step
// (coalesced, L2-resident stream), 16 broadcast h-reads, LDS partial reduce.
// NO persistent register arrays (1024-thr WGs spill past ~45 live dwords —
// measured rounds 3&5). fp32 h / fp32 accumulate.
__global__ __launch_bounds__(1024) void k_lstm(const float* __restrict__ gin,
                 const uint4* __restrict__ W16, float* __restrict__ hseq){
  int tid = threadIdx.x;
  int b = blockIdx.x & 31, d = blockIdx.x >> 5;
  int kpart = tid >> 8;
  const uint4* wq = W16 + (size_t)d*32*1024 + tid;   // + q*1024 per q
  const float* gb = gin + (size_t)d*GIN_PER_DIR + (size_t)b*SS*1024;

  __shared__ float hs[256];
  __shared__ float4 gl4[1024];
  if (tid < 256) hs[tid] = 0.f;
  float c = 0.f;
  __syncthreads();

  const float4* hs4 = (const float4*)hs;
  for (int s = 0; s < SS; ++s){
    int t = d ? (SS-1-s) : s;
    float4 gv = make_float4(0.f,0.f,0.f,0.f);
    if (tid < 256) gv = ((const float4*)(gb + (size_t)t*1024))[tid];  // prefetch

    float ai = 0.f, af = 0.f, ag = 0.f, ao = 0.f;
    #pragma unroll 4
    for (int u = 0; u < 8; ++u){
      float4 ha = hs4[kpart*16 + u*2];
      float4 hb = hs4[kpart*16 + u*2 + 1];
      uint4 w0 = wq[(u*4+0)*1024];
      uint4 w1 = wq[(u*4+1)*1024];
      uint4 w2 = wq[(u*4+2)*1024];
      uint4 w3 = wq[(u*4+3)*1024];
      ai = mac8(w0, ha, hb, ai);
      af = mac8(w1, ha, hb, af);
      ag = mac8(w2, ha, hb, ag);
      ao = mac8(w3, ha, hb, ao);
    }
    gl4[tid] = make_float4(ai, af, ag, ao);
    __syncthreads();
    if (tid < 256){
      float4 p0 = gl4[tid], p1 = gl4[256+tid], p2 = gl4[512+tid], p3 = gl4[768+tid];
      float iv = sigm (p0.x + p1.x + p2.x + p3.x + gv.x);
      float fv = sigm (p0.y + p1.y + p2.y + p3.y + gv.y);
      float gg = tanhf(p0.z + p1.z + p2.z + p3.z + gv.z);
      float ov = sigm (p0.w + p1.w + p2.w + p3.w + gv.w);
      c = fv*c + iv*gg;
      float hv = ov*tanhf(c);
      hs[tid] = hv;
      hseq[((size_t)(b*SS + t))*512 + d*256 + tid] = hv;
    }
    __syncthreads();
  }
}

// -------- tag logits: emit[row][t] = hseq[row] . W_tag[t] + b_tag[t] --------
__global__ void k_emit(const float* __restrict__ hseq, const float* __restrict__ Wtag,
                       const float* __restrict__ btag, float* __restrict__ emit){
  int id = blockIdx.x*256 + threadIdx.x;
  if (id >= BS*TT) return;
  int row = id / TT, tg = id - row*TT;
  const float4* hp = (const float4*)(hseq + (size_t)row*512);
  const float4* wp = (const float4*)(Wtag + (size_t)tg*512);
  float acc = btag[tg];
  #pragma unroll 8
  for (int k = 0; k < 128; ++k){
    float4 h = hp[k], w = wp[k];
    acc += h.x*w.x + h.y*w.y + h.z*w.z + h.w*w.w;
  }
  emit[id] = acc;
}

// -------- CRF NLL (forward algorithm + gold score), one wave per batch --------
__global__ void k_crf(const float* __restrict__ emit, const int* __restrict__ msk,
                      const int* __restrict__ lab, const float* __restrict__ trans,
                      float* __restrict__ nll){
  int b = blockIdx.x, tid = threadIdx.x;
  __shared__ float tr[361];
  __shared__ float al[19];
  for (int i = tid; i < 361; i += 64) tr[i] = trans[i];
  const float* eb = emit + (size_t)b*SS*TT;
  const int* mb = msk + b*SS;
  const int* lb = lab + b*SS;
  __syncthreads();
  float gp = 0.f; int ln = 0;
  for (int t = tid; t < SS; t += 64){
    int m = mb[t];
    ln += m;
    if (m){
      int l = lb[t];
      int p = t ? lb[t-1] : START_TAG;
      gp += tr[p*19 + l] + eb[t*19 + l];
    }
  }
  for (int off = 32; off; off >>= 1){ gp += __shfl_down(gp, off); ln += __shfl_down(ln, off); }
  float gold = 0.f;
  if (tid == 0){
    int lt = lb[ln - 1];
    gold = gp + tr[lt*19 + STOP_TAG];
  }
  if (tid < 19) al[tid] = eb[tid] + tr[START_TAG*19 + tid];
  __syncthreads();
  for (int t = 1; t < SS; ++t){
    int m = mb[t];
    float nv = 0.f;
    if (tid < 19){
      float mx = -1e30f;
      for (int p = 0; p < 19; ++p){ float v = al[p] + tr[p*19 + tid]; mx = fmaxf(mx, v); }
      float sum = 0.f;
      for (int p = 0; p < 19; ++p) sum += expf(al[p] + tr[p*19 + tid] - mx);
      nv = mx + logf(sum) + eb[t*19 + tid];
    }
    __syncthreads();
    if (tid < 19 && m) al[tid] = nv;
    __syncthreads();
  }
  if (tid == 0){
    float mx = -1e30f;
    for (int c2 = 0; c2 < 19; ++c2) mx = fmaxf(mx, al[c2] + tr[c2*19 + STOP_TAG]);
    float sum = 0.f;
    for (int c2 = 0; c2 < 19; ++c2) sum += expf(al[c2] + tr[c2*19 + STOP_TAG] - mx);
    nll[b] = (mx + logf(sum)) - gold;
  }
}

// -------- Viterbi decode, one wave per batch; writes tags (as float) to d_out[1..] --------
__global__ void k_vit(const float* __restrict__ emit, const int* __restrict__ msk,
                      const float* __restrict__ trans, int* __restrict__ ptr,
                      float* __restrict__ out){
  int b = blockIdx.x, tid = threadIdx.x;
  __shared__ float tr[361];
  __shared__ float dl[19];
  __shared__ int tg[256];
  for (int i = tid; i < 361; i += 64) tr[i] = trans[i];
  const float* eb = emit + (size_t)b*SS*TT;
  const int* mb = msk + b*SS;
  int* pb = ptr + (size_t)b*SS*TT;
  if (tid < 19) dl[tid] = eb[tid] + tr[START_TAG*19 + tid];
  __syncthreads();
  for (int t = 1; t < SS; ++t){
    int m = mb[t];
    float best = -1e30f; int bp = 0;
    if (tid < 19){
      for (int p = 0; p < 19; ++p){
        float v = dl[p] + tr[p*19 + tid];
        if (v > best){ best = v; bp = p; }       // strict > == first-max (jnp.argmax)
      }
    }
    __syncthreads();
    if (tid < 19){
      if (m){ dl[tid] = best + eb[t*19 + tid]; pb[t*19 + tid] = bp; }
      else  { pb[t*19 + tid] = tid; }            // identity pass-through when padded
    }
    __syncthreads();
  }
  if (tid == 0){
    float bv = -1e30f; int bl = 0;
    for (int c2 = 0; c2 < 19; ++c2){
      float v = dl[c2] + tr[c2*19 + STOP_TAG];
      if (v > bv){ bv = v; bl = c2; }
    }
    tg[SS-1] = bl;
    for (int t = SS-1; t > 0; --t) tg[t-1] = pb[t*19 + tg[t]];
  }
  __syncthreads();
  for (int t = tid; t < SS; t += 64)
    out[1 + b*SS + t] = (float)(tg[t] * mb[t]);
}

// -------- final loss reduce: d_out[0] = sum(nll)/B --------
__global__ void k_final(const float* __restrict__ nll, float* __restrict__ out){
  int tid = threadIdx.x;
  float v = (tid < 32) ? nll[tid] : 0.f;
  for (int off = 32; off; off >>= 1) v += __shfl_down(v, off);
  if (tid == 0) out[0] = v * (1.0f/32.0f);
}

extern "C" void kernel_launch(void* const* d_in, const int* in_sizes, int n_in,
                              void* d_out, int out_size, void* d_ws, size_t ws_size,
                              hipStream_t stream){
  const int*   wi    = (const int*)d_in[0];
  const int*   msk   = (const int*)d_in[1];
  const int*   lab   = (const int*)d_in[2];
  // d_in[3] labels_token, d_in[4] data_type: unused (data_type==1 branch)
  const float* emb   = (const float*)d_in[5];
  const float* Wih_f = (const float*)d_in[6];
  const float* Whh_f = (const float*)d_in[7];
  const float* bih_f = (const float*)d_in[8];
  const float* bhh_f = (const float*)d_in[9];
  const float* Wih_b = (const float*)d_in[10];
  const float* Whh_b = (const float*)d_in[11];
  const float* bih_b = (const float*)d_in[12];
  const float* bhh_b = (const float*)d_in[13];
  const float* Wtag  = (const float*)d_in[14];
  const float* btag  = (const float*)d_in[15];
  const float* trans = (const float*)d_in[16];

  float* ws   = (float*)d_ws;
  float* x    = ws;
  float* WT   = ws + 2490368;
  float* bias = ws + 3112960;
  unsigned int* W16u = (unsigned int*)(ws + 3115008);
  uint4* W16  = (uint4*)W16u;
  float* gin  = ws + 3639296;
  float* hseq = ws + 20416512;
  float* emit = ws + 24610816;
  int*   ptr  = (int*)(ws + 24766464);
  float* nll  = ws + 24922112;
  float* out  = (float*)d_out;

  hipLaunchKernelGGL(k_embed,      dim3(2432),    dim3(256),  0, stream, wi, msk, emb, x);
  hipLaunchKernelGGL(k_prep_wt,    dim3(2440),    dim3(256),  0, stream,
                     Wih_f, Wih_b, bih_f, bhh_f, bih_b, bhh_b, WT, bias);
  hipLaunchKernelGGL(k_prep_whh16, dim3(1024),    dim3(256),  0, stream, Whh_f, Whh_b, W16u);
  hipLaunchKernelGGL(k_gemm,       dim3(32,128),  dim3(256),  0, stream, x, WT, bias, gin);
  hipLaunchKernelGGL(k_lstm,       dim3(64),      dim3(1024), 0, stream, gin, W16, hseq);
  hipLaunchKernelGGL(k_emit,       dim3(608),     dim3(256),  0, stream, hseq, Wtag, btag, emit);
  hipLaunchKernelGGL(k_crf,        dim3(32),      dim3(64),   0, stream, emit, msk, lab, trans, nll);
  hipLaunchKernelGGL(k_vit,        dim3(32),      dim3(64),   0, stream, emit, msk, trans, ptr, out);
  hipLaunchKernelGGL(k_final,      dim3(1),       dim3(64),   0, stream, nll, out);
}